// Round 7
// baseline (349.685 us; speedup 1.0000x reference)
//
#include <hip/hip_runtime.h>
#include <hip/hip_bf16.h>
#include <cstdint>
#include <cstddef>

typedef unsigned short u16;
typedef __bf16 bf16x8 __attribute__((ext_vector_type(8)));
typedef float  f32x4  __attribute__((ext_vector_type(4)));
typedef u16    u16x8  __attribute__((ext_vector_type(8)));
typedef u16    u16x4  __attribute__((ext_vector_type(4)));
typedef short  s16x4  __attribute__((ext_vector_type(4)));

#define MFMA16(A_, B_, C_) __builtin_amdgcn_mfma_f32_16x16x32_bf16((A_), (B_), (C_), 0, 0, 0)
#define MFMA16K16(A_, B_, C_) __builtin_amdgcn_mfma_f32_16x16x16bf16_1k((A_), (B_), (C_), 0, 0, 0)

#define LOG2E 1.4426950408889634f

__device__ __forceinline__ u16 f2bf(float f) {
  return __builtin_bit_cast(u16, (__bf16)f);
}
__device__ __forceinline__ float bf2f(u16 v) {
  return (float)__builtin_bit_cast(__bf16, v);
}

// async global->LDS, 16B per lane. lds must be wave-uniform base; HW adds lane*16.
__device__ __forceinline__ void async16(u16* lds, const u16* g) {
  __builtin_amdgcn_global_load_lds(
      (const __attribute__((address_space(1))) unsigned int*)g,
      (__attribute__((address_space(3))) unsigned int*)lds, 16, 0, 0);
}

// ---------------- prep kernels ----------------

__global__ void cvt_f32_bf16(const float* __restrict__ src, u16* __restrict__ dst, int n4) {
  int i = blockIdx.x * 256 + threadIdx.x;
  if (i < n4) {
    const float4 v = ((const float4*)src)[i];
    u16x4 o;
    o[0] = f2bf(v.x); o[1] = f2bf(v.y); o[2] = f2bf(v.z); o[3] = f2bf(v.w);
    ((u16x4*)dst)[i] = o;
  }
}

__global__ void bn_prep(const float* __restrict__ g, const float* __restrict__ b,
                        const float* __restrict__ rm, const float* __restrict__ rv,
                        float* __restrict__ alpha, float* __restrict__ beta,
                        int n, float scale) {
  int i = blockIdx.x * 256 + threadIdx.x;
  if (i < n) {
    float a0 = g[i] * rsqrtf(rv[i] + 1e-5f);
    alpha[i] = a0 * scale;
    beta[i]  = (b[i] - rm[i] * a0) * scale;
  }
}

// bias (x log2e) in PV-fragment order: [h][qt3][kt40][tid256][half2][n2][j4]
__global__ void bias_expand_frag(const float* __restrict__ attn_bias, const int* __restrict__ idxs,
                                 u16* __restrict__ bias_frag, int n_off) {
  int i = blockIdx.x * 256 + threadIdx.x;
  if (i >= 8 * 3 * 40 * 256 * 16) return;
  const int e16  = i & 15;
  const int half = e16 >> 3;
  const int n    = (e16 >> 2) & 1;
  const int j    = e16 & 3;
  const int tid  = (i >> 4) & 255;
  int v = i >> 12;          // (h*3+qt)*40 + kt
  const int kt = v % 40; v /= 40;
  const int qt = v % 3;
  const int h  = v / 3;
  const int w = tid >> 6, lr = (tid >> 4) & 3, lc = tid & 15;
  int q = qt * 128 + w * 32 + half * 16 + lc;
  if (q > 319) q = 319;
  const int k = kt * 32 + n * 16 + lr * 4 + j;
  bias_frag[i] = f2bf(attn_bias[h * n_off + idxs[q * 1280 + k]] * LOG2E);
}

// ---------------- GEMM 1: kv = x @ W_kv^T, BN, scatter to K-phys / V-phys ----------------
// Per (bh, kt32): K = 32 rows x 64ch, 16B chunk c at c^(r&7)       (b128 reads)
// V = 128 d-rows x 32 keys (64B), 8B chunk hc at (hc+d)&7          (b64 reads)

__global__ __launch_bounds__(256) void gemm_kv(
    const u16* __restrict__ A, const u16* __restrict__ Wt,
    const float* __restrict__ alpha, const float* __restrict__ beta,
    u16* __restrict__ k_buf, u16* __restrict__ vt_buf) {
  __shared__ __align__(16) u16 As[128 * 64];
  __shared__ __align__(16) u16 Bs[128 * 64];
  const int tid  = threadIdx.x;
  const int lane = tid & 63;
  const int w    = tid >> 6;
  const int wr   = (w >> 1) * 64, wc = (w & 1) * 64;
  const int lr   = lane >> 4, lc = lane & 15;
  const int m0   = blockIdx.x * 128;
  const int n0   = blockIdx.y * 128;
  const int scol  = (lane & 7) * 8;
  f32x4 acc[4][4] = {};

  for (int kt = 0; kt < 256; kt += 64) {
    if (kt) __syncthreads();
#pragma unroll
    for (int i = 0; i < 4; ++i) {
      const int row = w * 32 + i * 8 + (lane >> 3);
      async16(&As[(w * 32 + i * 8) * 64], A  + (size_t)(m0 + row) * 256 + kt + scol);
      async16(&Bs[(w * 32 + i * 8) * 64], Wt + (size_t)(n0 + row) * 256 + kt + scol);
    }
    __syncthreads();
#pragma unroll
    for (int kk = 0; kk < 2; ++kk) {
      bf16x8 af[4], bff[4];
#pragma unroll
      for (int m = 0; m < 4; ++m)
        af[m] = *(const bf16x8*)(&As[(wr + m * 16 + lc) * 64 + kk * 32 + lr * 8]);
#pragma unroll
      for (int n = 0; n < 4; ++n)
        bff[n] = *(const bf16x8*)(&Bs[(wc + n * 16 + lc) * 64 + kk * 32 + lr * 8]);
#pragma unroll
      for (int m = 0; m < 4; ++m)
#pragma unroll
        for (int n = 0; n < 4; ++n)
          acc[m][n] = MFMA16(af[m], bff[n], acc[m][n]);
    }
  }

  const int jr = lr * 4;
#pragma unroll
  for (int m = 0; m < 4; ++m) {
    const int r0  = m0 + wr + m * 16 + jr;
    const int b   = r0 / 1280;
    const int np0 = r0 - b * 1280;          // global key, 4-aligned
    const int kt  = np0 >> 5;
    const int kl  = np0 & 31;               // key-in-tile, 4-aligned
#pragma unroll
    for (int n = 0; n < 4; ++n) {
      const int c    = n0 + wc + n * 16 + lc;
      const float al = alpha[c], be = beta[c];
      const int head = c / 192;
      const int off  = c - head * 192;
      const size_t bh = (size_t)(b * 8 + head);
      if (off < 64) {
        const size_t base = ((bh * 40 + kt) << 11);
#pragma unroll
        for (int j = 0; j < 4; ++j) {
          const int r = kl + j;
          k_buf[base + (r << 6) + ((((off >> 3) ^ (r & 7)) << 3)) + (off & 7)] =
              f2bf(acc[m][n][j] * al + be);
        }
      } else {
        const int d = off - 64;
        u16x4 pk;
#pragma unroll
        for (int j = 0; j < 4; ++j) pk[j] = f2bf(acc[m][n][j] * al + be);
        const size_t dst = ((size_t)(bh * 40 + kt) << 12) + d * 32 +
                           ((((kl >> 2) + d) & 7) << 2);
        *(u16x4*)(&vt_buf[dst]) = pk;
      }
    }
  }
}

// ---------------- GEMM 2: q = subsample(x) @ W_q^T, BN, *(0.125*log2e folded) ----------------

__device__ __forceinline__ int sub_src_row(int qr) {
  if (qr < 256) return ((qr >> 4) * 64) + ((qr & 15) * 2);
  int rr = qr - 256;
  return 1024 + ((rr >> 3) * 32) + ((rr & 7) * 2);
}

__global__ __launch_bounds__(256) void gemm_q(
    const u16* __restrict__ X, const u16* __restrict__ Wt,
    const float* __restrict__ alpha, const float* __restrict__ beta,
    u16* __restrict__ q_buf) {
  __shared__ __align__(16) u16 As[128 * 64];
  __shared__ __align__(16) u16 Bs[128 * 64];
  const int tid  = threadIdx.x;
  const int lane = tid & 63;
  const int w    = tid >> 6;
  const int wr   = (w >> 1) * 64, wc = (w & 1) * 64;
  const int lr   = lane >> 4, lc = lane & 15;
  const int m0   = blockIdx.x * 128;
  const int n0   = blockIdx.y * 128;
  const int scol  = (lane & 7) * 8;
  f32x4 acc[4][4] = {};

  for (int kt = 0; kt < 256; kt += 64) {
    if (kt) __syncthreads();
#pragma unroll
    for (int i = 0; i < 4; ++i) {
      const int row = w * 32 + i * 8 + (lane >> 3);
      const int gr  = m0 + row;
      const int bb  = gr / 320;
      const int qr  = gr - bb * 320;
      async16(&As[(w * 32 + i * 8) * 64],
              X + (size_t)(bb * 1280 + sub_src_row(qr)) * 256 + kt + scol);
      async16(&Bs[(w * 32 + i * 8) * 64], Wt + (size_t)(n0 + row) * 256 + kt + scol);
    }
    __syncthreads();
#pragma unroll
    for (int kk = 0; kk < 2; ++kk) {
      bf16x8 af[4], bff[4];
#pragma unroll
      for (int m = 0; m < 4; ++m)
        af[m] = *(const bf16x8*)(&As[(wr + m * 16 + lc) * 64 + kk * 32 + lr * 8]);
#pragma unroll
      for (int n = 0; n < 4; ++n)
        bff[n] = *(const bf16x8*)(&Bs[(wc + n * 16 + lc) * 64 + kk * 32 + lr * 8]);
#pragma unroll
      for (int m = 0; m < 4; ++m)
#pragma unroll
        for (int n = 0; n < 4; ++n)
          acc[m][n] = MFMA16(af[m], bff[n], acc[m][n]);
    }
  }

  const int jr = lr * 4;
#pragma unroll
  for (int m = 0; m < 4; ++m) {
#pragma unroll
    for (int n = 0; n < 4; ++n) {
      const int c    = n0 + wc + n * 16 + lc;   // < 512
      const float al = alpha[c], be = beta[c];
      const int head = c >> 6, kd = c & 63;
#pragma unroll
      for (int j = 0; j < 4; ++j) {
        const int r  = m0 + wr + m * 16 + jr + j;
        const int b  = r / 320;
        const int qr = r - b * 320;
        q_buf[((size_t)(b * 8 + head) * 320 + qr) * 64 + kd] = f2bf(acc[m][n][j] * al + be);
      }
    }
  }
}

// ---------------- attention ----------------
// Block = 128 q-rows (4 waves x 2 halves of 16). KVBLK=32. Swapped QK^T, in-reg P,
// K=16 PV. No-max softmax (S statically bounded; log2e pre-folded -> exp2 direct).
// Bias enters as MFMA C-init. global_load_lds dbuf staging, 1 barrier/tile.

__global__ __launch_bounds__(256, 4) void attn_kernel(
    const u16* __restrict__ q_buf, const u16* __restrict__ kphys,
    const u16* __restrict__ vphys, const u16* __restrict__ bias_frag,
    u16* __restrict__ o_buf) {
  __shared__ __align__(16) u16 Kb[2][2048];
  __shared__ __align__(16) u16 Vb[2][4096];
  const int tid  = threadIdx.x;
  const int lane = tid & 63;
  const int w    = tid >> 6;
  const int lr   = lane >> 4, lc = lane & 15, jr = lr * 4;
  // XCD swizzle: 96 consecutive per XCD -> 32 (b,h) groups of 3 q-tiles
  const int g   = blockIdx.x;
  const int f   = (g & 7) * 96 + (g >> 3);
  const int qt  = f % 3;
  const int bh_ = f / 3;
  const int h = bh_ & 7, b = bh_ >> 3;
  const size_t bh = (size_t)bh_;

  bf16x8 bq[2][2];
#pragma unroll
  for (int hf = 0; hf < 2; ++hf) {
    int q = qt * 128 + w * 32 + hf * 16 + lc;
    if (q > 319) q = 319;
    const u16* qp = q_buf + (bh * 320 + q) * 64 + lr * 8;
    bq[hf][0] = *(const bf16x8*)(qp);
    bq[hf][1] = *(const bf16x8*)(qp + 32);
  }

  f32x4 oacc[2][8] = {};
  float lacc[2] = {0.f, 0.f};

  const u16* kt_base   = kphys + bh * (40 * 2048);
  const u16* vt_base   = vphys + bh * (40 * 4096);
  const u16* bias_base = bias_frag + (((size_t)(h * 3 + qt) * 40) * 256 + tid) * 16;

  u16x8 bbA[2], bbB[2];

  auto issue = [&](int buf, int kt) {
    async16(&Kb[buf][w * 512], kt_base + kt * 2048 + w * 512 + lane * 8);
    const u16* vs = vt_base + kt * 4096 + (w * 2) * 512 + lane * 8;
    async16(&Vb[buf][(w * 2) * 512], vs);
    async16(&Vb[buf][(w * 2 + 1) * 512], vs + 512);
  };
  auto gbias = [&](int kt, u16x8* dst) {
    const u16* bp = bias_base + (size_t)kt * 4096;
    dst[0] = *(const u16x8*)(bp);
    dst[1] = *(const u16x8*)(bp + 8);
  };

  auto step = [&](int buf, int kt, const u16x8* bb, u16x8* bbn) {
    __syncthreads();                        // buf's loads landed (auto vmcnt(0))
    if (kt < 39) issue(buf ^ 1, kt + 1);    // next tile under this tile's compute
    gbias(kt < 39 ? kt + 1 : 39, bbn);

    const u16* Ksb = Kb[buf];
    const u16* Vsb = Vb[buf];

    // S^T = K Q^T with bias as C-init; n in {0,1} key-chunks of 16
    f32x4 s[2][2];
    __builtin_amdgcn_s_setprio(1);
#pragma unroll
    for (int n = 0; n < 2; ++n) {
      const u16* kp = Ksb + (n * 16 + lc) * 64;
      const bf16x8 kf0 = *(const bf16x8*)(kp + ((lr ^ (lc & 7)) << 3));
      const bf16x8 kf1 = *(const bf16x8*)(kp + (((4 + lr) ^ (lc & 7)) << 3));
#pragma unroll
      for (int hf = 0; hf < 2; ++hf) {
        const u16* bptr = (const u16*)bb;
        f32x4 t;
#pragma unroll
        for (int j = 0; j < 4; ++j) t[j] = bf2f(bptr[hf * 8 + n * 4 + j]);
        t = MFMA16(kf0, bq[hf][0], t);
        t = MFMA16(kf1, bq[hf][1], t);
        s[hf][n] = t;
      }
    }
    __builtin_amdgcn_s_setprio(0);

    // P = exp2(S') in-register; in-lane partial row-sum
    s16x4 pa[2][2];
#pragma unroll
    for (int hf = 0; hf < 2; ++hf) {
      float ssum = 0.f;
#pragma unroll
      for (int n = 0; n < 2; ++n) {
        u16x4 pk;
#pragma unroll
        for (int j = 0; j < 4; ++j) {
          const float e = exp2f(s[hf][n][j]);
          ssum += e;
          pk[j] = f2bf(e);
        }
        pa[hf][n] = __builtin_bit_cast(s16x4, pk);
      }
      lacc[hf] += ssum;
    }

    // PV: V b64 reads shared by both halves (rotation layout: conflict-free)
    __builtin_amdgcn_s_setprio(1);
#pragma unroll
    for (int nc = 0; nc < 8; ++nc) {
      const int d = nc * 16 + lc;
      const u16* vrow = Vsb + d * 32;
#pragma unroll
      for (int t = 0; t < 2; ++t) {
        const int ph = (t * 4 + lr + d) & 7;
        const s16x4 vf = __builtin_bit_cast(s16x4, *(const u16x4*)(vrow + ph * 4));
        oacc[0][nc] = MFMA16K16(pa[0][t], vf, oacc[0][nc]);
        oacc[1][nc] = MFMA16K16(pa[1][t], vf, oacc[1][nc]);
      }
    }
    __builtin_amdgcn_s_setprio(0);
  };

  issue(0, 0);
  gbias(0, bbA);
#pragma unroll 1
  for (int kt = 0; kt < 40; kt += 2) {
    step(0, kt, bbA, bbB);
    step(1, kt + 1, bbB, bbA);
  }

#pragma unroll
  for (int hf = 0; hf < 2; ++hf) {
    float l = lacc[hf];
    l += __shfl_xor(l, 16);
    l += __shfl_xor(l, 32);
    float invl[4];
#pragma unroll
    for (int j = 0; j < 4; ++j) invl[j] = 1.f / __shfl(l, jr + j);
#pragma unroll
    for (int nc = 0; nc < 8; ++nc)
#pragma unroll
      for (int j = 0; j < 4; ++j) {
        const int qrow = qt * 128 + w * 32 + hf * 16 + jr + j;
        if (qrow < 320) {
          const float xv = oacc[hf][nc][j] * invl[j];
          const float hs = xv * fminf(fmaxf(xv + 3.f, 0.f), 6.f) * (1.f / 6.f);
          o_buf[((size_t)b * 320 + qrow) * 1024 + h * 128 + nc * 16 + lc] = f2bf(hs);
        }
      }
  }
}

// ---------------- GEMM 3: out = hswish(o) @ W_p^T, BN (f32 out) ----------------

__global__ __launch_bounds__(256) void gemm_p(
    const u16* __restrict__ O, const u16* __restrict__ Wt,
    const float* __restrict__ alpha, const float* __restrict__ beta,
    float* __restrict__ out) {
  __shared__ __align__(16) u16 As[128 * 64];
  __shared__ __align__(16) u16 Bs[128 * 64];
  const int tid  = threadIdx.x;
  const int lane = tid & 63;
  const int w    = tid >> 6;
  const int wr   = (w >> 1) * 64, wc = (w & 1) * 64;
  const int lr   = lane >> 4, lc = lane & 15;
  const int m0   = blockIdx.x * 128;
  const int n0   = blockIdx.y * 128;
  const int scol  = (lane & 7) * 8;
  f32x4 acc[4][4] = {};

  for (int kt = 0; kt < 1024; kt += 64) {
    if (kt) __syncthreads();
#pragma unroll
    for (int i = 0; i < 4; ++i) {
      const int row = w * 32 + i * 8 + (lane >> 3);
      async16(&As[(w * 32 + i * 8) * 64], O  + (size_t)(m0 + row) * 1024 + kt + scol);
      async16(&Bs[(w * 32 + i * 8) * 64], Wt + (size_t)(n0 + row) * 1024 + kt + scol);
    }
    __syncthreads();
#pragma unroll
    for (int kk = 0; kk < 2; ++kk) {
      bf16x8 af[4], bff[4];
#pragma unroll
      for (int m = 0; m < 4; ++m)
        af[m] = *(const bf16x8*)(&As[(wr + m * 16 + lc) * 64 + kk * 32 + lr * 8]);
#pragma unroll
      for (int n = 0; n < 4; ++n)
        bff[n] = *(const bf16x8*)(&Bs[(wc + n * 16 + lc) * 64 + kk * 32 + lr * 8]);
#pragma unroll
      for (int m = 0; m < 4; ++m)
#pragma unroll
        for (int n = 0; n < 4; ++n)
          acc[m][n] = MFMA16(af[m], bff[n], acc[m][n]);
    }
  }

  const int jr = lr * 4;
#pragma unroll
  for (int m = 0; m < 4; ++m) {
#pragma unroll
    for (int n = 0; n < 4; ++n) {
      const int c = n0 + wc + n * 16 + lc;   // < 384
      const float al = alpha[c], be = beta[c];
#pragma unroll
      for (int j = 0; j < 4; ++j) {
        const int r = m0 + wr + m * 16 + jr + j;
        out[(size_t)r * 384 + c] = acc[m][n][j] * al + be;
      }
    }
  }
}

// ---------------- launch ----------------

extern "C" void kernel_launch(void* const* d_in, const int* in_sizes, int n_in,
                              void* d_out, int out_size, void* d_ws, size_t ws_size,
                              hipStream_t stream) {
  const float* x      = (const float*)d_in[0];
  const float* W_kv   = (const float*)d_in[1];
  const float* g_kv   = (const float*)d_in[2];
  const float* b_kv   = (const float*)d_in[3];
  const float* rm_kv  = (const float*)d_in[4];
  const float* rv_kv  = (const float*)d_in[5];
  const float* W_q    = (const float*)d_in[6];
  const float* g_q    = (const float*)d_in[7];
  const float* b_q    = (const float*)d_in[8];
  const float* rm_q   = (const float*)d_in[9];
  const float* rv_q   = (const float*)d_in[10];
  const float* W_p    = (const float*)d_in[11];
  const float* g_p    = (const float*)d_in[12];
  const float* b_p    = (const float*)d_in[13];
  const float* rm_p   = (const float*)d_in[14];
  const float* rv_p   = (const float*)d_in[15];
  const float* attn_bias = (const float*)d_in[16];
  const int*   bias_idxs = (const int*)d_in[17];
  const int n_off = in_sizes[16] / 8;

  char* ws = (char*)d_ws;
  size_t off = 0;
  auto alloc = [&](size_t bytes) -> void* {
    void* p = ws + off;
    off += (bytes + 255) & ~(size_t)255;
    return p;
  };
  u16* x_bf    = (u16*)alloc((size_t)40960 * 256 * 2);
  u16* wkv_bf  = (u16*)alloc((size_t)1536 * 256 * 2);
  u16* wq_bf   = (u16*)alloc((size_t)512 * 256 * 2);
  u16* wp_bf   = (u16*)alloc((size_t)384 * 1024 * 2);
  float* al_kv = (float*)alloc(1536 * 4);
  float* be_kv = (float*)alloc(1536 * 4);
  float* al_q  = (float*)alloc(512 * 4);
  float* be_q  = (float*)alloc(512 * 4);
  float* al_p  = (float*)alloc(384 * 4);
  float* be_p  = (float*)alloc(384 * 4);
  u16* k_buf   = (u16*)alloc((size_t)256 * 40 * 2048 * 2);
  u16* vt_buf  = (u16*)alloc((size_t)256 * 40 * 4096 * 2);
  u16* q_buf   = (u16*)alloc((size_t)32 * 8 * 320 * 64 * 2);
  u16* bias_fr = (u16*)alloc((size_t)8 * 3 * 40 * 256 * 16 * 2);
  u16* o_buf   = (u16*)alloc((size_t)32 * 320 * 1024 * 2);
  (void)ws_size; (void)n_in; (void)out_size;

  cvt_f32_bf16<<<(2621440 + 255) / 256, 256, 0, stream>>>(x, x_bf, 2621440);
  cvt_f32_bf16<<<(98304 + 255) / 256, 256, 0, stream>>>(W_kv, wkv_bf, 98304);
  cvt_f32_bf16<<<(32768 + 255) / 256, 256, 0, stream>>>(W_q, wq_bf, 32768);
  cvt_f32_bf16<<<(98304 + 255) / 256, 256, 0, stream>>>(W_p, wp_bf, 98304);
  bn_prep<<<6, 256, 0, stream>>>(g_kv, b_kv, rm_kv, rv_kv, al_kv, be_kv, 1536, 1.0f);
  bn_prep<<<2, 256, 0, stream>>>(g_q, b_q, rm_q, rv_q, al_q, be_q, 512, 0.125f * LOG2E);
  bn_prep<<<2, 256, 0, stream>>>(g_p, b_p, rm_p, rv_p, al_p, be_p, 384, 1.0f);
  bias_expand_frag<<<(7864320 + 255) / 256, 256, 0, stream>>>(attn_bias, bias_idxs, bias_fr, n_off);

  gemm_kv<<<dim3(320, 12), 256, 0, stream>>>(x_bf, wkv_bf, al_kv, be_kv, k_buf, vt_buf);
  gemm_q<<<dim3(80, 4), 256, 0, stream>>>(x_bf, wq_bf, al_q, be_q, q_buf);
  attn_kernel<<<dim3(768), 256, 0, stream>>>(q_buf, k_buf, vt_buf, bias_fr, o_buf);
  gemm_p<<<dim3(80, 3), 256, 0, stream>>>(o_buf, wp_bf, al_p, be_p, (float*)d_out);
}

// Round 8
// 237.733 us; speedup vs baseline: 1.4709x; 1.4709x over previous
//
#include <hip/hip_runtime.h>
#include <hip/hip_bf16.h>
#include <cstdint>
#include <cstddef>

typedef unsigned short u16;
typedef __bf16 bf16x8 __attribute__((ext_vector_type(8)));
typedef float  f32x4  __attribute__((ext_vector_type(4)));
typedef u16    u16x8  __attribute__((ext_vector_type(8)));
typedef u16    u16x4  __attribute__((ext_vector_type(4)));
typedef short  s16x4  __attribute__((ext_vector_type(4)));

#define MFMA16(A_, B_, C_) __builtin_amdgcn_mfma_f32_16x16x32_bf16((A_), (B_), (C_), 0, 0, 0)
#define MFMA16K16(A_, B_, C_) __builtin_amdgcn_mfma_f32_16x16x16bf16_1k((A_), (B_), (C_), 0, 0, 0)

#define LOG2E 1.4426950408889634f

__device__ __forceinline__ u16 f2bf(float f) {
  return __builtin_bit_cast(u16, (__bf16)f);
}
__device__ __forceinline__ float bf2f(u16 v) {
  return (float)__builtin_bit_cast(__bf16, v);
}

// async global->LDS, 16B per lane. lds must be wave-uniform base; HW adds lane*16.
__device__ __forceinline__ void async16(u16* lds, const u16* g) {
  __builtin_amdgcn_global_load_lds(
      (const __attribute__((address_space(1))) unsigned int*)g,
      (__attribute__((address_space(3))) unsigned int*)lds, 16, 0, 0);
}

// ---------------- prep kernels ----------------

__global__ void cvt_f32_bf16(const float* __restrict__ src, u16* __restrict__ dst, int n4) {
  int i = blockIdx.x * 256 + threadIdx.x;
  if (i < n4) {
    const float4 v = ((const float4*)src)[i];
    u16x4 o;
    o[0] = f2bf(v.x); o[1] = f2bf(v.y); o[2] = f2bf(v.z); o[3] = f2bf(v.w);
    ((u16x4*)dst)[i] = o;
  }
}

__global__ void bn_prep(const float* __restrict__ g, const float* __restrict__ b,
                        const float* __restrict__ rm, const float* __restrict__ rv,
                        float* __restrict__ alpha, float* __restrict__ beta,
                        int n, float scale) {
  int i = blockIdx.x * 256 + threadIdx.x;
  if (i < n) {
    float a0 = g[i] * rsqrtf(rv[i] + 1e-5f);
    alpha[i] = a0 * scale;
    beta[i]  = (b[i] - rm[i] * a0) * scale;
  }
}

// bias (x log2e) in PV-fragment order: [h][qt3][kt40][tid256][half2][n2][j4]
__global__ void bias_expand_frag(const float* __restrict__ attn_bias, const int* __restrict__ idxs,
                                 u16* __restrict__ bias_frag, int n_off) {
  int i = blockIdx.x * 256 + threadIdx.x;
  if (i >= 8 * 3 * 40 * 256 * 16) return;
  const int e16  = i & 15;
  const int half = e16 >> 3;
  const int n    = (e16 >> 2) & 1;
  const int j    = e16 & 3;
  const int tid  = (i >> 4) & 255;
  int v = i >> 12;          // (h*3+qt)*40 + kt
  const int kt = v % 40; v /= 40;
  const int qt = v % 3;
  const int h  = v / 3;
  const int w = tid >> 6, lr = (tid >> 4) & 3, lc = tid & 15;
  const int nn = e16 >> 2 & 1;
  (void)n;
  int q = qt * 128 + w * 32 + half * 16 + lc;
  if (q > 319) q = 319;
  const int k = kt * 32 + nn * 16 + lr * 4 + j;
  bias_frag[i] = f2bf(attn_bias[h * n_off + idxs[q * 1280 + k]] * LOG2E);
}

// ---------------- GEMM 1: kv = x @ W_kv^T, BN, scatter to K-phys / V-phys ----------------
// Per (bh, kt32): K = 32 rows x 64ch, 16B chunk c at c^(r&7)       (b128 reads)
// V = 128 d-rows x 32 keys (64B), 8B chunk hc at (hc+d)&7          (b64 reads)

__global__ __launch_bounds__(256) void gemm_kv(
    const u16* __restrict__ A, const u16* __restrict__ Wt,
    const float* __restrict__ alpha, const float* __restrict__ beta,
    u16* __restrict__ k_buf, u16* __restrict__ vt_buf) {
  __shared__ __align__(16) u16 As[128 * 64];
  __shared__ __align__(16) u16 Bs[128 * 64];
  const int tid  = threadIdx.x;
  const int lane = tid & 63;
  const int w    = tid >> 6;
  const int wr   = (w >> 1) * 64, wc = (w & 1) * 64;
  const int lr   = lane >> 4, lc = lane & 15;
  const int m0   = blockIdx.x * 128;
  const int n0   = blockIdx.y * 128;
  const int scol  = (lane & 7) * 8;
  f32x4 acc[4][4] = {};

  for (int kt = 0; kt < 256; kt += 64) {
    if (kt) __syncthreads();
#pragma unroll
    for (int i = 0; i < 4; ++i) {
      const int row = w * 32 + i * 8 + (lane >> 3);
      async16(&As[(w * 32 + i * 8) * 64], A  + (size_t)(m0 + row) * 256 + kt + scol);
      async16(&Bs[(w * 32 + i * 8) * 64], Wt + (size_t)(n0 + row) * 256 + kt + scol);
    }
    __syncthreads();
#pragma unroll
    for (int kk = 0; kk < 2; ++kk) {
      bf16x8 af[4], bff[4];
#pragma unroll
      for (int m = 0; m < 4; ++m)
        af[m] = *(const bf16x8*)(&As[(wr + m * 16 + lc) * 64 + kk * 32 + lr * 8]);
#pragma unroll
      for (int n = 0; n < 4; ++n)
        bff[n] = *(const bf16x8*)(&Bs[(wc + n * 16 + lc) * 64 + kk * 32 + lr * 8]);
#pragma unroll
      for (int m = 0; m < 4; ++m)
#pragma unroll
        for (int n = 0; n < 4; ++n)
          acc[m][n] = MFMA16(af[m], bff[n], acc[m][n]);
    }
  }

  const int jr = lr * 4;
#pragma unroll
  for (int m = 0; m < 4; ++m) {
    const int r0  = m0 + wr + m * 16 + jr;
    const int b   = r0 / 1280;
    const int np0 = r0 - b * 1280;          // global key, 4-aligned
    const int kt  = np0 >> 5;
    const int kl  = np0 & 31;               // key-in-tile, 4-aligned
#pragma unroll
    for (int n = 0; n < 4; ++n) {
      const int c    = n0 + wc + n * 16 + lc;
      const float al = alpha[c], be = beta[c];
      const int head = c / 192;
      const int off  = c - head * 192;
      const size_t bh = (size_t)(b * 8 + head);
      if (off < 64) {
        const size_t base = ((bh * 40 + kt) << 11);
#pragma unroll
        for (int j = 0; j < 4; ++j) {
          const int r = kl + j;
          k_buf[base + (r << 6) + ((((off >> 3) ^ (r & 7)) << 3)) + (off & 7)] =
              f2bf(acc[m][n][j] * al + be);
        }
      } else {
        const int d = off - 64;
        u16x4 pk;
#pragma unroll
        for (int j = 0; j < 4; ++j) pk[j] = f2bf(acc[m][n][j] * al + be);
        const size_t dst = ((size_t)(bh * 40 + kt) << 12) + d * 32 +
                           ((((kl >> 2) + d) & 7) << 2);
        *(u16x4*)(&vt_buf[dst]) = pk;
      }
    }
  }
}

// ---------------- GEMM 2: q = subsample(x) @ W_q^T, BN, *(0.125*log2e folded) ----------------

__device__ __forceinline__ int sub_src_row(int qr) {
  if (qr < 256) return ((qr >> 4) * 64) + ((qr & 15) * 2);
  int rr = qr - 256;
  return 1024 + ((rr >> 3) * 32) + ((rr & 7) * 2);
}

__global__ __launch_bounds__(256) void gemm_q(
    const u16* __restrict__ X, const u16* __restrict__ Wt,
    const float* __restrict__ alpha, const float* __restrict__ beta,
    u16* __restrict__ q_buf) {
  __shared__ __align__(16) u16 As[128 * 64];
  __shared__ __align__(16) u16 Bs[128 * 64];
  const int tid  = threadIdx.x;
  const int lane = tid & 63;
  const int w    = tid >> 6;
  const int wr   = (w >> 1) * 64, wc = (w & 1) * 64;
  const int lr   = lane >> 4, lc = lane & 15;
  const int m0   = blockIdx.x * 128;
  const int n0   = blockIdx.y * 128;
  const int scol  = (lane & 7) * 8;
  f32x4 acc[4][4] = {};

  for (int kt = 0; kt < 256; kt += 64) {
    if (kt) __syncthreads();
#pragma unroll
    for (int i = 0; i < 4; ++i) {
      const int row = w * 32 + i * 8 + (lane >> 3);
      const int gr  = m0 + row;
      const int bb  = gr / 320;
      const int qr  = gr - bb * 320;
      async16(&As[(w * 32 + i * 8) * 64],
              X + (size_t)(bb * 1280 + sub_src_row(qr)) * 256 + kt + scol);
      async16(&Bs[(w * 32 + i * 8) * 64], Wt + (size_t)(n0 + row) * 256 + kt + scol);
    }
    __syncthreads();
#pragma unroll
    for (int kk = 0; kk < 2; ++kk) {
      bf16x8 af[4], bff[4];
#pragma unroll
      for (int m = 0; m < 4; ++m)
        af[m] = *(const bf16x8*)(&As[(wr + m * 16 + lc) * 64 + kk * 32 + lr * 8]);
#pragma unroll
      for (int n = 0; n < 4; ++n)
        bff[n] = *(const bf16x8*)(&Bs[(wc + n * 16 + lc) * 64 + kk * 32 + lr * 8]);
#pragma unroll
      for (int m = 0; m < 4; ++m)
#pragma unroll
        for (int n = 0; n < 4; ++n)
          acc[m][n] = MFMA16(af[m], bff[n], acc[m][n]);
    }
  }

  const int jr = lr * 4;
#pragma unroll
  for (int m = 0; m < 4; ++m) {
#pragma unroll
    for (int n = 0; n < 4; ++n) {
      const int c    = n0 + wc + n * 16 + lc;   // < 512
      const float al = alpha[c], be = beta[c];
      const int head = c >> 6, kd = c & 63;
#pragma unroll
      for (int j = 0; j < 4; ++j) {
        const int r  = m0 + wr + m * 16 + jr + j;
        const int b  = r / 320;
        const int qr = r - b * 320;
        q_buf[((size_t)(b * 8 + head) * 320 + qr) * 64 + kd] = f2bf(acc[m][n][j] * al + be);
      }
    }
  }
}

// ---------------- attention ----------------
// Block = 128 q-rows (4 waves x 2 halves of 16). KVBLK=32. Swapped QK^T, in-reg P,
// K=16 PV. No-max softmax (S statically bounded; log2e pre-folded -> exp2 direct).
// Bias enters as MFMA C-init. global_load_lds dbuf staging, 1 barrier/tile.
// NO min-wave launch bound: R7's (256,4) forced VGPR=64 -> accumulator spills
// (WRITE_SIZE 20->556MB). Natural allocation ~100-110 VGPR is correct here.

__global__ __launch_bounds__(256) void attn_kernel(
    const u16* __restrict__ q_buf, const u16* __restrict__ kphys,
    const u16* __restrict__ vphys, const u16* __restrict__ bias_frag,
    u16* __restrict__ o_buf) {
  __shared__ __align__(16) u16 Kb[2][2048];
  __shared__ __align__(16) u16 Vb[2][4096];
  const int tid  = threadIdx.x;
  const int lane = tid & 63;
  const int w    = tid >> 6;
  const int lr   = lane >> 4, lc = lane & 15, jr = lr * 4;
  // XCD swizzle: 96 consecutive per XCD -> 32 (b,h) groups of 3 q-tiles
  const int g   = blockIdx.x;
  const int f   = (g & 7) * 96 + (g >> 3);
  const int qt  = f % 3;
  const int bh_ = f / 3;
  const int h = bh_ & 7, b = bh_ >> 3;
  const size_t bh = (size_t)bh_;

  bf16x8 bq[2][2];
#pragma unroll
  for (int hf = 0; hf < 2; ++hf) {
    int q = qt * 128 + w * 32 + hf * 16 + lc;
    if (q > 319) q = 319;
    const u16* qp = q_buf + (bh * 320 + q) * 64 + lr * 8;
    bq[hf][0] = *(const bf16x8*)(qp);
    bq[hf][1] = *(const bf16x8*)(qp + 32);
  }

  f32x4 oacc[2][8] = {};
  float lacc[2] = {0.f, 0.f};

  const u16* kt_base   = kphys + bh * (40 * 2048);
  const u16* vt_base   = vphys + bh * (40 * 4096);
  const u16* bias_base = bias_frag + (((size_t)(h * 3 + qt) * 40) * 256 + tid) * 16;

  u16x8 bbA[2], bbB[2];

  auto issue = [&](int buf, int kt) {
    async16(&Kb[buf][w * 512], kt_base + kt * 2048 + w * 512 + lane * 8);
    const u16* vs = vt_base + kt * 4096 + (w * 2) * 512 + lane * 8;
    async16(&Vb[buf][(w * 2) * 512], vs);
    async16(&Vb[buf][(w * 2 + 1) * 512], vs + 512);
  };
  auto gbias = [&](int kt, u16x8* dst) {
    const u16* bp = bias_base + (size_t)kt * 4096;
    dst[0] = *(const u16x8*)(bp);
    dst[1] = *(const u16x8*)(bp + 8);
  };

  auto step = [&](int buf, int kt, const u16x8* bb, u16x8* bbn) {
    __syncthreads();                        // buf's loads landed (auto vmcnt(0))
    if (kt < 39) issue(buf ^ 1, kt + 1);    // next tile under this tile's compute
    gbias(kt < 39 ? kt + 1 : 39, bbn);

    const u16* Ksb = Kb[buf];
    const u16* Vsb = Vb[buf];

    // S^T = K Q^T with bias as C-init; n in {0,1} key-chunks of 16
    f32x4 s[2][2];
    __builtin_amdgcn_s_setprio(1);
#pragma unroll
    for (int n = 0; n < 2; ++n) {
      const u16* kp = Ksb + (n * 16 + lc) * 64;
      const bf16x8 kf0 = *(const bf16x8*)(kp + ((lr ^ (lc & 7)) << 3));
      const bf16x8 kf1 = *(const bf16x8*)(kp + (((4 + lr) ^ (lc & 7)) << 3));
#pragma unroll
      for (int hf = 0; hf < 2; ++hf) {
        const u16* bptr = (const u16*)bb;
        f32x4 t;
#pragma unroll
        for (int j = 0; j < 4; ++j) t[j] = bf2f(bptr[hf * 8 + n * 4 + j]);
        t = MFMA16(kf0, bq[hf][0], t);
        t = MFMA16(kf1, bq[hf][1], t);
        s[hf][n] = t;
      }
    }
    __builtin_amdgcn_s_setprio(0);

    // P = exp2(S') in-register; in-lane partial row-sum
    s16x4 pa[2][2];
#pragma unroll
    for (int hf = 0; hf < 2; ++hf) {
      float ssum = 0.f;
#pragma unroll
      for (int n = 0; n < 2; ++n) {
        u16x4 pk;
#pragma unroll
        for (int j = 0; j < 4; ++j) {
          const float e = exp2f(s[hf][n][j]);
          ssum += e;
          pk[j] = f2bf(e);
        }
        pa[hf][n] = __builtin_bit_cast(s16x4, pk);
      }
      lacc[hf] += ssum;
    }

    // PV: V b64 reads shared by both halves (rotation layout: conflict-free)
    __builtin_amdgcn_s_setprio(1);
#pragma unroll
    for (int nc = 0; nc < 8; ++nc) {
      const int d = nc * 16 + lc;
      const u16* vrow = Vsb + d * 32;
#pragma unroll
      for (int t = 0; t < 2; ++t) {
        const int ph = (t * 4 + lr + d) & 7;
        const s16x4 vf = __builtin_bit_cast(s16x4, *(const u16x4*)(vrow + ph * 4));
        oacc[0][nc] = MFMA16K16(pa[0][t], vf, oacc[0][nc]);
        oacc[1][nc] = MFMA16K16(pa[1][t], vf, oacc[1][nc]);
      }
    }
    __builtin_amdgcn_s_setprio(0);
  };

  issue(0, 0);
  gbias(0, bbA);
#pragma unroll 1
  for (int kt = 0; kt < 40; kt += 2) {
    step(0, kt, bbA, bbB);
    step(1, kt + 1, bbB, bbA);
  }

#pragma unroll
  for (int hf = 0; hf < 2; ++hf) {
    float l = lacc[hf];
    l += __shfl_xor(l, 16);
    l += __shfl_xor(l, 32);
    float invl[4];
#pragma unroll
    for (int j = 0; j < 4; ++j) invl[j] = 1.f / __shfl(l, jr + j);
#pragma unroll
    for (int nc = 0; nc < 8; ++nc)
#pragma unroll
      for (int j = 0; j < 4; ++j) {
        const int qrow = qt * 128 + w * 32 + hf * 16 + jr + j;
        if (qrow < 320) {
          const float xv = oacc[hf][nc][j] * invl[j];
          const float hs = xv * fminf(fmaxf(xv + 3.f, 0.f), 6.f) * (1.f / 6.f);
          o_buf[((size_t)b * 320 + qrow) * 1024 + h * 128 + nc * 16 + lc] = f2bf(hs);
        }
      }
  }
}

// ---------------- GEMM 3: out = hswish(o) @ W_p^T, BN (f32 out) ----------------

__global__ __launch_bounds__(256) void gemm_p(
    const u16* __restrict__ O, const u16* __restrict__ Wt,
    const float* __restrict__ alpha, const float* __restrict__ beta,
    float* __restrict__ out) {
  __shared__ __align__(16) u16 As[128 * 64];
  __shared__ __align__(16) u16 Bs[128 * 64];
  const int tid  = threadIdx.x;
  const int lane = tid & 63;
  const int w    = tid >> 6;
  const int wr   = (w >> 1) * 64, wc = (w & 1) * 64;
  const int lr   = lane >> 4, lc = lane & 15;
  const int m0   = blockIdx.x * 128;
  const int n0   = blockIdx.y * 128;
  const int scol  = (lane & 7) * 8;
  f32x4 acc[4][4] = {};

  for (int kt = 0; kt < 1024; kt += 64) {
    if (kt) __syncthreads();
#pragma unroll
    for (int i = 0; i < 4; ++i) {
      const int row = w * 32 + i * 8 + (lane >> 3);
      async16(&As[(w * 32 + i * 8) * 64], O  + (size_t)(m0 + row) * 1024 + kt + scol);
      async16(&Bs[(w * 32 + i * 8) * 64], Wt + (size_t)(n0 + row) * 1024 + kt + scol);
    }
    __syncthreads();
#pragma unroll
    for (int kk = 0; kk < 2; ++kk) {
      bf16x8 af[4], bff[4];
#pragma unroll
      for (int m = 0; m < 4; ++m)
        af[m] = *(const bf16x8*)(&As[(wr + m * 16 + lc) * 64 + kk * 32 + lr * 8]);
#pragma unroll
      for (int n = 0; n < 4; ++n)
        bff[n] = *(const bf16x8*)(&Bs[(wc + n * 16 + lc) * 64 + kk * 32 + lr * 8]);
#pragma unroll
      for (int m = 0; m < 4; ++m)
#pragma unroll
        for (int n = 0; n < 4; ++n)
          acc[m][n] = MFMA16(af[m], bff[n], acc[m][n]);
    }
  }

  const int jr = lr * 4;
#pragma unroll
  for (int m = 0; m < 4; ++m) {
#pragma unroll
    for (int n = 0; n < 4; ++n) {
      const int c = n0 + wc + n * 16 + lc;   // < 384
      const float al = alpha[c], be = beta[c];
#pragma unroll
      for (int j = 0; j < 4; ++j) {
        const int r = m0 + wr + m * 16 + jr + j;
        out[(size_t)r * 384 + c] = acc[m][n][j] * al + be;
      }
    }
  }
}

// ---------------- launch ----------------

extern "C" void kernel_launch(void* const* d_in, const int* in_sizes, int n_in,
                              void* d_out, int out_size, void* d_ws, size_t ws_size,
                              hipStream_t stream) {
  const float* x      = (const float*)d_in[0];
  const float* W_kv   = (const float*)d_in[1];
  const float* g_kv   = (const float*)d_in[2];
  const float* b_kv   = (const float*)d_in[3];
  const float* rm_kv  = (const float*)d_in[4];
  const float* rv_kv  = (const float*)d_in[5];
  const float* W_q    = (const float*)d_in[6];
  const float* g_q    = (const float*)d_in[7];
  const float* b_q    = (const float*)d_in[8];
  const float* rm_q   = (const float*)d_in[9];
  const float* rv_q   = (const float*)d_in[10];
  const float* W_p    = (const float*)d_in[11];
  const float* g_p    = (const float*)d_in[12];
  const float* b_p    = (const float*)d_in[13];
  const float* rm_p   = (const float*)d_in[14];
  const float* rv_p   = (const float*)d_in[15];
  const float* attn_bias = (const float*)d_in[16];
  const int*   bias_idxs = (const int*)d_in[17];
  const int n_off = in_sizes[16] / 8;

  char* ws = (char*)d_ws;
  size_t off = 0;
  auto alloc = [&](size_t bytes) -> void* {
    void* p = ws + off;
    off += (bytes + 255) & ~(size_t)255;
    return p;
  };
  u16* x_bf    = (u16*)alloc((size_t)40960 * 256 * 2);
  u16* wkv_bf  = (u16*)alloc((size_t)1536 * 256 * 2);
  u16* wq_bf   = (u16*)alloc((size_t)512 * 256 * 2);
  u16* wp_bf   = (u16*)alloc((size_t)384 * 1024 * 2);
  float* al_kv = (float*)alloc(1536 * 4);
  float* be_kv = (float*)alloc(1536 * 4);
  float* al_q  = (float*)alloc(512 * 4);
  float* be_q  = (float*)alloc(512 * 4);
  float* al_p  = (float*)alloc(384 * 4);
  float* be_p  = (float*)alloc(384 * 4);
  u16* k_buf   = (u16*)alloc((size_t)256 * 40 * 2048 * 2);
  u16* vt_buf  = (u16*)alloc((size_t)256 * 40 * 4096 * 2);
  u16* q_buf   = (u16*)alloc((size_t)32 * 8 * 320 * 64 * 2);
  u16* bias_fr = (u16*)alloc((size_t)8 * 3 * 40 * 256 * 16 * 2);
  u16* o_buf   = (u16*)alloc((size_t)32 * 320 * 1024 * 2);
  (void)ws_size; (void)n_in; (void)out_size;

  cvt_f32_bf16<<<(2621440 + 255) / 256, 256, 0, stream>>>(x, x_bf, 2621440);
  cvt_f32_bf16<<<(98304 + 255) / 256, 256, 0, stream>>>(W_kv, wkv_bf, 98304);
  cvt_f32_bf16<<<(32768 + 255) / 256, 256, 0, stream>>>(W_q, wq_bf, 32768);
  cvt_f32_bf16<<<(98304 + 255) / 256, 256, 0, stream>>>(W_p, wp_bf, 98304);
  bn_prep<<<6, 256, 0, stream>>>(g_kv, b_kv, rm_kv, rv_kv, al_kv, be_kv, 1536, 1.0f);
  bn_prep<<<2, 256, 0, stream>>>(g_q, b_q, rm_q, rv_q, al_q, be_q, 512, 0.125f * LOG2E);
  bn_prep<<<2, 256, 0, stream>>>(g_p, b_p, rm_p, rv_p, al_p, be_p, 384, 1.0f);
  bias_expand_frag<<<(7864320 + 255) / 256, 256, 0, stream>>>(attn_bias, bias_idxs, bias_fr, n_off);

  gemm_kv<<<dim3(320, 12), 256, 0, stream>>>(x_bf, wkv_bf, al_kv, be_kv, k_buf, vt_buf);
  gemm_q<<<dim3(80, 4), 256, 0, stream>>>(x_bf, wq_bf, al_q, be_q, q_buf);
  attn_kernel<<<dim3(768), 256, 0, stream>>>(q_buf, k_buf, vt_buf, bias_fr, o_buf);
  gemm_p<<<dim3(80, 3), 256, 0, stream>>>(o_buf, wp_bf, al_p, be_p, (float*)d_out);
}